// Round 4
// baseline (256.108 us; speedup 1.0000x reference)
//
#include <hip/hip_runtime.h>

// out = x @ H, H = 4096x4096 Sylvester Hadamard (+/-1). H[i][j] =
// (-1)^popcount(i&j) is symmetric -> each output row is the Walsh-Hadamard
// transform of the input row: O(N log N) butterflies instead of a 275-GFLOP
// fp32 matmul. Memory-bound: 256 MiB logical traffic, ~30 us pipe floor
// (HBM ~29.5 us with L3 hits, LDS pipe ~25 us). H (d_in[1]) never read.
//
// R4 = R3 resubmitted verbatim (R3 failed on container infra, not kernel).
// R3 change vs R2: R2 measured 78.5 us with NO pipe saturated (HBM 32%,
// VALU 16%, LDS ~32%) -> phase-lockstep: all blocks burst HBM, then burst
// LDS, serially. Fix: persistent blocks (2048) each process 4 rows with
// cross-row register prefetch. The prefetch must survive barriers, so
// __syncthreads() (which drains vmcnt(0) before s_barrier) is replaced by
// raw `s_waitcnt lgkmcnt(0); s_barrier` inline asm with a memory clobber:
// LDS-correct (lgkmcnt covers all DS ops; LDS is CU-local), global loads
// stay in flight.

constexpr int N = 4096;

typedef float f32x4 __attribute__((ext_vector_type(4)));

// LDS bank-conflict swizzle: XOR bits 6-8 of the element index into bits 2-4.
// Preserves bits 0-1 -> 16 B alignment survives. Scalar phases land at worst
// 2 lanes/bank per wave (2-way aliasing is free on gfx950, m136). Verified:
// SQ_LDS_BANK_CONFLICT == 0 in R2.
__device__ __forceinline__ int swz(int i) {
    return i ^ (((i >> 6) & 7) << 2);
}

// Workgroup barrier that does NOT drain vmcnt: waits only for LDS (lgkmcnt)
// and keeps pending global loads in flight across the barrier.
#define LDS_BARRIER() asm volatile("s_waitcnt lgkmcnt(0)\n\ts_barrier" ::: "memory")

__global__ __launch_bounds__(256) void fwht4096_kernel(const float* __restrict__ x,
                                                       float* __restrict__ out,
                                                       int rows) {
    __shared__ __align__(16) float lds[N];
    const int t = threadIdx.x;
    const int stride = gridDim.x;

    int row = blockIdx.x;

    // Prefetch first row into registers (coalesced float4: 1 KiB/wave-inst).
    f32x4 pre[4];
    {
        const float* __restrict__ xr = x + (size_t)row * N;
#pragma unroll
        for (int k = 0; k < 4; ++k)
            pre[k] = *reinterpret_cast<const f32x4*>(xr + 1024 * k + 4 * t);
    }

    for (; row < rows; row += stride) {
        float* __restrict__ yr = out + (size_t)row * N;

        // ---- Phase 0: consume prefetch; stages on bits 0,1 (within float4)
        // and bits 10,11 (k): h = 1, 2, 1024, 2048.
        float r[4][4];
#pragma unroll
        for (int k = 0; k < 4; ++k) {
            r[k][0] = pre[k].x; r[k][1] = pre[k].y;
            r[k][2] = pre[k].z; r[k][3] = pre[k].w;
        }
#pragma unroll
        for (int k = 0; k < 4; ++k) {  // h=1 then h=2
            float a0 = r[k][0] + r[k][1];
            float a1 = r[k][0] - r[k][1];
            float a2 = r[k][2] + r[k][3];
            float a3 = r[k][2] - r[k][3];
            r[k][0] = a0 + a2;
            r[k][1] = a1 + a3;
            r[k][2] = a0 - a2;
            r[k][3] = a1 - a3;
        }
#pragma unroll
        for (int j = 0; j < 4; ++j) {  // h=1024 then h=2048
            float a0 = r[0][j] + r[1][j];
            float a1 = r[0][j] - r[1][j];
            float a2 = r[2][j] + r[3][j];
            float a3 = r[2][j] - r[3][j];
            r[0][j] = a0 + a2;
            r[1][j] = a1 + a3;
            r[2][j] = a0 - a2;
            r[3][j] = a1 - a3;
        }
#pragma unroll
        for (int k = 0; k < 4; ++k) {
            const int i0 = 1024 * k + 4 * t;
            f32x4 v = {r[k][0], r[k][1], r[k][2], r[k][3]};
            *reinterpret_cast<f32x4*>(&lds[swz(i0)]) = v;
        }

        // ---- Issue next row's loads NOW; they stay pending across the
        // LDS phases (~1500 cyc of latency cover). Block-uniform branch.
        {
            const int nrow = row + stride;
            if (nrow < rows) {
                const float* __restrict__ xr = x + (size_t)nrow * N;
#pragma unroll
                for (int k = 0; k < 4; ++k)
                    pre[k] = *reinterpret_cast<const f32x4*>(xr + 1024 * k + 4 * t);
            }
        }
        LDS_BARRIER();

        // ---- Phase 1: own bits 2-5 (m), stages h = 4, 8, 16, 32.
        {
            float v[16];
            const int base1 = (t & 3) | (((t >> 2) & 15) << 6) | ((t >> 6) << 10);
#pragma unroll
            for (int m = 0; m < 16; ++m) v[m] = lds[swz(base1 | (m << 2))];
#pragma unroll
            for (int b = 1; b < 16; b <<= 1) {
#pragma unroll
                for (int m = 0; m < 16; ++m) {
                    if ((m & b) == 0) {
                        const float a = v[m], c = v[m | b];
                        v[m]     = a + c;
                        v[m | b] = a - c;
                    }
                }
            }
#pragma unroll
            for (int m = 0; m < 16; ++m) lds[swz(base1 | (m << 2))] = v[m];
        }
        LDS_BARRIER();

        // ---- Phase 2: own bits 6-9 (m), stages h = 64, 128, 256, 512.
        // In-place write-back (per-thread address sets partition the row).
        {
            float w[16];
            const int base2 = (t & 63) | ((t >> 6) << 10);
#pragma unroll
            for (int m = 0; m < 16; ++m) w[m] = lds[swz(base2 | (m << 6))];
#pragma unroll
            for (int b = 1; b < 16; b <<= 1) {
#pragma unroll
                for (int m = 0; m < 16; ++m) {
                    if ((m & b) == 0) {
                        const float a = w[m], c = w[m | b];
                        w[m]     = a + c;
                        w[m | b] = a - c;
                    }
                }
            }
#pragma unroll
            for (int m = 0; m < 16; ++m) lds[swz(base2 | (m << 6))] = w[m];
        }
        LDS_BARRIER();

        // ---- Phase 3: vectorized epilogue. b128 LDS reads in load layout,
        // 4x float4 NT stores (1 KiB/wave-inst; out never re-read).
#pragma unroll
        for (int k = 0; k < 4; ++k) {
            const int i0 = 1024 * k + 4 * t;
            const f32x4 v = *reinterpret_cast<const f32x4*>(&lds[swz(i0)]);
            __builtin_nontemporal_store(v, reinterpret_cast<f32x4*>(yr + i0));
        }

        // Protect LDS reuse: all waves' epilogue reads must finish before
        // anyone starts next row's phase-0 writes.
        LDS_BARRIER();
    }
}

extern "C" void kernel_launch(void* const* d_in, const int* in_sizes, int n_in,
                              void* d_out, int out_size, void* d_ws, size_t ws_size,
                              hipStream_t stream) {
    (void)n_in; (void)d_ws; (void)ws_size; (void)out_size;
    const float* x = (const float*)d_in[0];  // [8192, 4096] fp32
    float* out = (float*)d_out;              // [8192, 4096] fp32
    const int rows = in_sizes[0] / N;        // 8192
    const int blocks = 2048;                 // 8 per CU; each does rows/2048 = 4 rows
    fwht4096_kernel<<<blocks, 256, 0, stream>>>(x, out, rows);
}